// Round 15
// baseline (372.805 us; speedup 1.0000x reference)
//
#include <hip/hip_runtime.h>
#include <hip/hip_fp16.h>

#define N_NODES   50000
#define N_EDGES   800000
#define NF        32
#define DE        64
#define NH        8
#define CT        512     // NH*DE
#define DMLP      512
#define NG        2000
#define NEGS      0.2f

// ---------------- helpers ----------------

__device__ inline float4 fma4(float a, float4 v, float4 c) {
    c.x = fmaf(a, v.x, c.x); c.y = fmaf(a, v.y, c.y);
    c.z = fmaf(a, v.z, c.z); c.w = fmaf(a, v.w, c.w);
    return c;
}

__device__ inline float edge_w(float e) {
    e = e > 0.f ? e : NEGS * e;
    return __expf(e);      // no max-subtraction: ratio Σw·v / Σw is invariant
}

__device__ inline unsigned packh2(float a, float b) {
    __half2 h = __floats2half2_rn(a, b);
    return *reinterpret_cast<unsigned*>(&h);
}
__device__ inline float2 uph2(unsigned u) {
    __half2 h = *reinterpret_cast<__half2*>(&u);
    return __half22float2(h);
}
__device__ inline void unpack8(uint4 u, float* f) {
    float2 a = uph2(u.x), b = uph2(u.y), c = uph2(u.z), d = uph2(u.w);
    f[0] = a.x; f[1] = a.y; f[2] = b.x; f[3] = b.y;
    f[4] = c.x; f[5] = c.y; f[6] = d.x; f[7] = d.y;
}

// ---------------- setup mega-kernel (all dependency-free prep) ----------------
// ranges: alpha1 | cnt/cur/total init | U1 | goffs | B2 | out=fcb3 | x->fp16 | fcW->fp16

#define SB_A 1563   // ceil(400000/256)
#define SB_I 196
#define SB_U 64
#define SB_G 196
#define SB_B 2
#define SB_O 8      // 2000/256
#define SB_X 782    // ceil(50000*32/8/256)
#define SB_F 256    // 2*512*512/8/256 (fcW1+fcW2 -> fp16; also warms L3)

__global__ __launch_bounds__(256) void setup_k(
        const float* __restrict__ x, const float* __restrict__ W1,
        const float* __restrict__ as1, const float* __restrict__ ad1,
        const float* __restrict__ W2, const float* __restrict__ as2,
        const float* __restrict__ ad2, const int* __restrict__ batch,
        const float* __restrict__ fcb3,
        const float* __restrict__ fcW1, const float* __restrict__ fcW2,
        int* __restrict__ cnt, int* __restrict__ cur, int* __restrict__ total,
        float* __restrict__ U1, int* __restrict__ goff,
        float* __restrict__ B2s, float* __restrict__ B2d,
        float* __restrict__ as_, float* __restrict__ ad_,
        float* __restrict__ outp, __half* __restrict__ xh,
        __half* __restrict__ fw1h, __half* __restrict__ fw2h) {
    int b = blockIdx.x;
    int tid = threadIdx.x;
    if (b < SB_A) {
        // layer-1 attention logits; B1 = W1·a computed per block into LDS
        __shared__ float bs[256], bd[256];
        {
            int c = tid >> 3, hd = tid & 7;
            const float* wr = W1 + c * 512 + hd * 64;
            const float* p1 = as1 + hd * 64;
            const float* p2 = ad1 + hd * 64;
            float s1 = 0.f, s2 = 0.f;
            #pragma unroll 8
            for (int f = 0; f < 64; ++f) { float w = wr[f]; s1 += w * p1[f]; s2 += w * p2[f]; }
            bs[tid] = s1; bd[tid] = s2;
        }
        __syncthreads();
        int gid = b * 256 + tid;
        if (gid < N_NODES * NH) {
            int n = gid >> 3, hd = gid & 7;
            const float4* xp = (const float4*)(x + (size_t)n * NF);
            float s1 = 0.f, s2 = 0.f;
            #pragma unroll
            for (int qq = 0; qq < NF / 4; ++qq) {
                float4 v = xp[qq];
                int b0 = qq * 32 + hd;
                s1 += v.x * bs[b0] + v.y * bs[b0 + 8] + v.z * bs[b0 + 16] + v.w * bs[b0 + 24];
                s2 += v.x * bd[b0] + v.y * bd[b0 + 8] + v.z * bd[b0 + 16] + v.w * bd[b0 + 24];
            }
            as_[gid] = s1;
            ad_[gid] = s2;
        }
    } else if (b < SB_A + SB_I) {
        int i = (b - SB_A) * 256 + tid;
        if (i < N_NODES) { cnt[i] = 1; cur[i] = 0; }   // 1 = self-loop
        if (i == 0) total[0] = 0;
    } else if (b < SB_A + SB_I + SB_U) {
        int i = (b - SB_A - SB_I) * 256 + tid;         // U1[hd*32+c][f] = W1[c][hd*64+f]/8
        int k = i >> 6, f = i & 63;
        int hd = k >> 5, c = k & 31;
        U1[i] = W1[c * 512 + hd * 64 + f] * 0.125f;
    } else if (b < SB_A + SB_I + SB_U + SB_G) {
        int i = (b - SB_A - SB_I - SB_U) * 256 + tid;
        if (i < N_NODES) {
            int bb = batch[i];
            if (i == 0) {
                for (int g = 0; g <= bb; ++g) goff[g] = 0;
            } else {
                int pb = batch[i - 1];
                for (int g = pb + 1; g <= bb; ++g) goff[g] = i;
            }
            if (i == N_NODES - 1) {
                for (int g = bb + 1; g <= NG; ++g) goff[g] = N_NODES;
            }
        }
    } else if (b < SB_A + SB_I + SB_U + SB_G + SB_B) {
        int i = (b - SB_A - SB_I - SB_U - SB_G) * 256 + tid;   // < 512
        int c = i >> 3, hd = i & 7;
        const float* wr = W2 + c * 512 + hd * 64;
        const float* p1 = as2 + hd * 64;
        const float* p2 = ad2 + hd * 64;
        float s1 = 0.f, s2 = 0.f;
        #pragma unroll 8
        for (int f = 0; f < 64; ++f) { float w = wr[f]; s1 += w * p1[f]; s2 += w * p2[f]; }
        B2s[i] = s1; B2d[i] = s2;
    } else if (b < SB_A + SB_I + SB_U + SB_G + SB_B + SB_O) {
        int i = (b - SB_A - SB_I - SB_U - SB_G - SB_B) * 256 + tid;
        if (i < NG) outp[i] = fcb3[0];
    } else if (b < SB_A + SB_I + SB_U + SB_G + SB_B + SB_O + SB_X) {
        // x -> fp16 (8 floats per thread)
        int i = (b - SB_A - SB_I - SB_U - SB_G - SB_B - SB_O) * 256 + tid;
        if (i < N_NODES * NF / 8) {
            const float4* src = (const float4*)x + (size_t)i * 2;
            float4 v0 = src[0], v1 = src[1];
            uint4 u;
            u.x = packh2(v0.x, v0.y); u.y = packh2(v0.z, v0.w);
            u.z = packh2(v1.x, v1.y); u.w = packh2(v1.z, v1.w);
            *(uint4*)(xh + (size_t)i * 8) = u;
        }
    } else {
        // fcW1/fcW2 -> fp16 (8 floats per thread); also pre-warms L3 for the MLP
        int i = (b - SB_A - SB_I - SB_U - SB_G - SB_B - SB_O - SB_X) * 256 + tid;
        const float* src = (i < 32768) ? fcW1 : fcW2;
        __half* dst = (i < 32768) ? fw1h : fw2h;
        int off = (i & 32767) * 8;
        const float4* s4 = (const float4*)(src + off);
        float4 v0 = s4[0], v1 = s4[1];
        uint4 u;
        u.x = packh2(v0.x, v0.y); u.y = packh2(v0.z, v0.w);
        u.z = packh2(v1.x, v1.y); u.w = packh2(v1.z, v1.w);
        *(uint4*)(dst + off) = u;
    }
}

// ---------------- CSR build ----------------

__global__ void hist_k(const int* __restrict__ ei, int* __restrict__ cnt) {
    int e = blockIdx.x * 256 + threadIdx.x;
    if (e < N_EDGES) atomicAdd(&cnt[ei[N_EDGES + e]], 1);   // row 1 = dst
}

__global__ void alloc_off_k(const int* __restrict__ cnt, int* __restrict__ off,
                            int* __restrict__ total) {
    int i = blockIdx.x * 256 + threadIdx.x;
    if (i < N_NODES) off[i] = atomicAdd(total, cnt[i]);
}

__global__ void scatter_k(const int* __restrict__ ei, const int* __restrict__ off,
                          int* __restrict__ cur, int* __restrict__ ssrc) {
    int e = blockIdx.x * 256 + threadIdx.x;
    if (e < N_EDGES) {
        int s = ei[e];
        int d = ei[N_EDGES + e];
        int p = off[d] + atomicAdd(&cur[d], 1);
        ssrc[p] = s;
    } else if (e < N_EDGES + N_NODES) {
        int i = e - N_EDGES;                    // self loop
        int p = off[i] + atomicAdd(&cur[i], 1);
        ssrc[p] = i;
    }
}

// ---------------- layer-1 aggregation over fp16 x (wave per node, unroll 8) ----------------

__global__ __launch_bounds__(256) void agg1_k(
        const __half* __restrict__ xh, const float* __restrict__ as_,
        const float* __restrict__ ad_, const int* __restrict__ ssrc,
        const int* __restrict__ off, const int* __restrict__ cnt,
        __half* __restrict__ aggx1h) {
    int wv = __builtin_amdgcn_readfirstlane(blockIdx.x * 4 + (threadIdx.x >> 6));
    if (wv >= N_NODES) return;
    int lane = threadIdx.x & 63;
    int hd = lane >> 3, q = lane & 7;
    int beg = off[wv], end = beg + cnt[wv];
    float adv = ad_[wv * NH + hd];

    float4 acc = {0.f, 0.f, 0.f, 0.f};
    float wsum = 0.f;
    int j = beg;
    for (; j + 8 <= end; j += 8) {
        int s[8];
        #pragma unroll
        for (int u = 0; u < 8; ++u) s[u] = ssrc[j + u];
        float e[8];
        #pragma unroll
        for (int u = 0; u < 8; ++u) e[u] = as_[s[u] * NH + hd];
        uint2 uu[8];
        #pragma unroll
        for (int u = 0; u < 8; ++u) uu[u] = *(const uint2*)(xh + (size_t)s[u] * NF + q * 4);
        #pragma unroll
        for (int u = 0; u < 8; ++u) {
            float w = edge_w(e[u] + adv);
            wsum += w;
            float2 a01 = uph2(uu[u].x), a23 = uph2(uu[u].y);
            acc.x = fmaf(w, a01.x, acc.x); acc.y = fmaf(w, a01.y, acc.y);
            acc.z = fmaf(w, a23.x, acc.z); acc.w = fmaf(w, a23.y, acc.w);
        }
    }
    for (; j + 4 <= end; j += 4) {
        int s0 = ssrc[j], s1 = ssrc[j + 1], s2 = ssrc[j + 2], s3 = ssrc[j + 3];
        float e0 = as_[s0 * NH + hd], e1 = as_[s1 * NH + hd];
        float e2 = as_[s2 * NH + hd], e3 = as_[s3 * NH + hd];
        uint2 u0 = *(const uint2*)(xh + (size_t)s0 * NF + q * 4);
        uint2 u1 = *(const uint2*)(xh + (size_t)s1 * NF + q * 4);
        uint2 u2 = *(const uint2*)(xh + (size_t)s2 * NF + q * 4);
        uint2 u3 = *(const uint2*)(xh + (size_t)s3 * NF + q * 4);
        float w0 = edge_w(e0 + adv), w1 = edge_w(e1 + adv);
        float w2 = edge_w(e2 + adv), w3 = edge_w(e3 + adv);
        wsum += (w0 + w1) + (w2 + w3);
        float2 a01, a23;
        a01 = uph2(u0.x); a23 = uph2(u0.y);
        acc.x = fmaf(w0, a01.x, acc.x); acc.y = fmaf(w0, a01.y, acc.y);
        acc.z = fmaf(w0, a23.x, acc.z); acc.w = fmaf(w0, a23.y, acc.w);
        a01 = uph2(u1.x); a23 = uph2(u1.y);
        acc.x = fmaf(w1, a01.x, acc.x); acc.y = fmaf(w1, a01.y, acc.y);
        acc.z = fmaf(w1, a23.x, acc.z); acc.w = fmaf(w1, a23.y, acc.w);
        a01 = uph2(u2.x); a23 = uph2(u2.y);
        acc.x = fmaf(w2, a01.x, acc.x); acc.y = fmaf(w2, a01.y, acc.y);
        acc.z = fmaf(w2, a23.x, acc.z); acc.w = fmaf(w2, a23.y, acc.w);
        a01 = uph2(u3.x); a23 = uph2(u3.y);
        acc.x = fmaf(w3, a01.x, acc.x); acc.y = fmaf(w3, a01.y, acc.y);
        acc.z = fmaf(w3, a23.x, acc.z); acc.w = fmaf(w3, a23.y, acc.w);
    }
    for (; j < end; ++j) {
        int s0 = ssrc[j];
        float w0 = edge_w(as_[s0 * NH + hd] + adv);
        uint2 u0 = *(const uint2*)(xh + (size_t)s0 * NF + q * 4);
        wsum += w0;
        float2 a01 = uph2(u0.x), a23 = uph2(u0.y);
        acc.x = fmaf(w0, a01.x, acc.x); acc.y = fmaf(w0, a01.y, acc.y);
        acc.z = fmaf(w0, a23.x, acc.z); acc.w = fmaf(w0, a23.y, acc.w);
    }
    float inv = 1.f / wsum;
    uint2 st;
    st.x = packh2(acc.x * inv, acc.y * inv);
    st.y = packh2(acc.z * inv, acc.w * inv);
    *(uint2*)(aggx1h + (size_t)wv * 256 + lane * 4) = st;   // [hd*32 + q*4] == lane*4
}

// ---------------- proj1 + alpha2 fused: hxh = fp16(aggx1h @ U1 + b1); as_/ad_ from fp32 ----

__global__ __launch_bounds__(256) void proj1a_k(
        const __half* __restrict__ Ah, const float* __restrict__ U1,
        const float* __restrict__ b1, const float* __restrict__ B2s,
        const float* __restrict__ B2d, __half* __restrict__ hxh,
        float* __restrict__ as_, float* __restrict__ ad_) {
    __shared__ float As[64][64];
    __shared__ float bs2[512], bd2[512];
    int t = threadIdx.x;
    int row0 = blockIdx.x * 64;
    for (int i = t; i < 512; i += 256) { bs2[i] = B2s[i]; bd2[i] = B2d[i]; }
    int rr = t & 63;
    int kb = (t >> 6) * 16;
    int r0 = (t >> 4) * 4;
    int c0 = (t & 15) * 4;
    float acc[4][4];
    #pragma unroll
    for (int i = 0; i < 4; ++i)
        #pragma unroll
        for (int j = 0; j < 4; ++j) acc[i][j] = 0.f;

    for (int kc = 0; kc < 256; kc += 64) {
        __syncthreads();
        {
            int grow = row0 + rr;
            const __half* ap = Ah + (size_t)grow * 256 + kc + kb;
            uint4 u0 = {0, 0, 0, 0}, u1 = {0, 0, 0, 0};
            if (grow < N_NODES) {
                u0 = *(const uint4*)(ap);
                u1 = *(const uint4*)(ap + 8);
            }
            float f[16];
            unpack8(u0, f);
            unpack8(u1, f + 8);
            #pragma unroll
            for (int i = 0; i < 16; ++i) As[kb + i][rr] = f[i];
        }
        __syncthreads();
        const float* wp = U1 + (size_t)kc * 64 + c0;
        #pragma unroll 4
        for (int k = 0; k < 64; ++k) {
            float4 a = *(const float4*)&As[k][r0];
            float4 w = *(const float4*)(wp + k * 64);
            acc[0][0] = fmaf(a.x, w.x, acc[0][0]); acc[0][1] = fmaf(a.x, w.y, acc[0][1]);
            acc[0][2] = fmaf(a.x, w.z, acc[0][2]); acc[0][3] = fmaf(a.x, w.w, acc[0][3]);
            acc[1][0] = fmaf(a.y, w.x, acc[1][0]); acc[1][1] = fmaf(a.y, w.y, acc[1][1]);
            acc[1][2] = fmaf(a.y, w.z, acc[1][2]); acc[1][3] = fmaf(a.y, w.w, acc[1][3]);
            acc[2][0] = fmaf(a.z, w.x, acc[2][0]); acc[2][1] = fmaf(a.z, w.y, acc[2][1]);
            acc[2][2] = fmaf(a.z, w.z, acc[2][2]); acc[2][3] = fmaf(a.z, w.w, acc[2][3]);
            acc[3][0] = fmaf(a.w, w.x, acc[3][0]); acc[3][1] = fmaf(a.w, w.y, acc[3][1]);
            acc[3][2] = fmaf(a.w, w.z, acc[3][2]); acc[3][3] = fmaf(a.w, w.w, acc[3][3]);
        }
    }
    __syncthreads();
    // write hx tile (with bias) into As as [row][col]
    float4 bv = *(const float4*)(b1 + c0);
    #pragma unroll
    for (int i = 0; i < 4; ++i) {
        As[r0 + i][c0 + 0] = acc[i][0] + bv.x;
        As[r0 + i][c0 + 1] = acc[i][1] + bv.y;
        As[r0 + i][c0 + 2] = acc[i][2] + bv.z;
        As[r0 + i][c0 + 3] = acc[i][3] + bv.w;
    }
    __syncthreads();
    // epilogue: thread t -> row = t>>2, col-slice sub = t&3 (cols sub*16..+16)
    int row = t >> 2, sub = t & 3;
    int grow = row0 + row;
    float ps[8], pd[8];
    #pragma unroll
    for (int hd = 0; hd < 8; ++hd) { ps[hd] = 0.f; pd[hd] = 0.f; }
    #pragma unroll 4
    for (int c2 = 0; c2 < 16; ++c2) {
        int c = sub * 16 + c2;
        float v = As[row][c];
        #pragma unroll
        for (int hd = 0; hd < 8; ++hd) {
            ps[hd] = fmaf(v, bs2[c * 8 + hd], ps[hd]);
            pd[hd] = fmaf(v, bd2[c * 8 + hd], pd[hd]);
        }
    }
    #pragma unroll
    for (int d = 1; d <= 2; d <<= 1) {
        #pragma unroll
        for (int hd = 0; hd < 8; ++hd) {
            ps[hd] += __shfl_xor(ps[hd], d, 64);
            pd[hd] += __shfl_xor(pd[hd], d, 64);
        }
    }
    if (grow < N_NODES) {
        int h0 = sub * 2;
        as_[grow * 8 + h0]     = ps[h0];
        as_[grow * 8 + h0 + 1] = ps[h0 + 1];
        ad_[grow * 8 + h0]     = pd[h0];
        ad_[grow * 8 + h0 + 1] = pd[h0 + 1];
        // fp16 store of cols sub*16..+16 (logits above were from fp32 - exact)
        const float* r = &As[row][sub * 16];
        uint4 u0, u1;
        u0.x = packh2(r[0],  r[1]);  u0.y = packh2(r[2],  r[3]);
        u0.z = packh2(r[4],  r[5]);  u0.w = packh2(r[6],  r[7]);
        u1.x = packh2(r[8],  r[9]);  u1.y = packh2(r[10], r[11]);
        u1.z = packh2(r[12], r[13]); u1.w = packh2(r[14], r[15]);
        *(uint4*)(hxh + (size_t)grow * 64 + sub * 16)     = u0;
        *(uint4*)(hxh + (size_t)grow * 64 + sub * 16 + 8) = u1;
    }
}

// ---------------- layer-2 agg (fp16 gather, packed fp16 accumulate, unroll 8) + pool + proj ----
// one block (4 waves) per graph; lane owns channels lane*8..+8 (head = lane>>3).
// fp16 accumulation is overflow-safe here: layer-2 logits sigma ~0.2 -> w in ~[0.5,2].

__device__ inline void acc8pk(float w, uint4 u, __half2& a0, __half2& a1,
                              __half2& a2, __half2& a3) {
    __half2 wh = __float2half2_rn(w);
    union { uint4 u4; __half2 h[4]; } c;
    c.u4 = u;
    a0 = __hfma2(wh, c.h[0], a0);
    a1 = __hfma2(wh, c.h[1], a1);
    a2 = __hfma2(wh, c.h[2], a2);
    a3 = __hfma2(wh, c.h[3], a3);
}

__global__ __launch_bounds__(256) void agg2gp_k(
        const __half* __restrict__ hxh, const float* __restrict__ as_,
        const float* __restrict__ ad_, const int* __restrict__ ssrc,
        const int* __restrict__ off, const int* __restrict__ cnt,
        const int* __restrict__ goff, const float* __restrict__ W2,
        const float* __restrict__ b2, float* __restrict__ g0) {
    int g = blockIdx.x;
    int w = threadIdx.x >> 6;
    int lane = threadIdx.x & 63;
    int hd = lane >> 3, q = lane & 7;
    int nbeg = goff[g], nend = goff[g + 1];

    __shared__ float sp[4][512];

    float4 p0 = {0.f, 0.f, 0.f, 0.f}, p1 = {0.f, 0.f, 0.f, 0.f};

    for (int nd0 = nbeg + w; nd0 < nend; nd0 += 4) {
        int nd = __builtin_amdgcn_readfirstlane(nd0);
        int beg = off[nd], end = beg + cnt[nd];
        float adv = ad_[nd * NH + hd];

        __half2 z = __float2half2_rn(0.f);
        __half2 ah0 = z, ah1 = z, ah2 = z, ah3 = z;
        float wsum = 0.f;
        int j = beg;
        for (; j + 8 <= end; j += 8) {
            int s[8];
            #pragma unroll
            for (int u = 0; u < 8; ++u) s[u] = ssrc[j + u];
            float e[8];
            #pragma unroll
            for (int u = 0; u < 8; ++u) e[u] = as_[s[u] * NH + hd];
            uint4 uu[8];
            #pragma unroll
            for (int u = 0; u < 8; ++u) uu[u] = *(const uint4*)(hxh + (size_t)s[u] * DE + q * 8);
            #pragma unroll
            for (int u = 0; u < 8; ++u) {
                float ww = edge_w(e[u] + adv);
                wsum += ww;
                acc8pk(ww, uu[u], ah0, ah1, ah2, ah3);
            }
        }
        for (; j + 4 <= end; j += 4) {
            int s0 = ssrc[j], s1 = ssrc[j + 1], s2 = ssrc[j + 2], s3 = ssrc[j + 3];
            float e0 = as_[s0 * NH + hd], e1 = as_[s1 * NH + hd];
            float e2 = as_[s2 * NH + hd], e3 = as_[s3 * NH + hd];
            uint4 u0 = *(const uint4*)(hxh + (size_t)s0 * DE + q * 8);
            uint4 u1 = *(const uint4*)(hxh + (size_t)s1 * DE + q * 8);
            uint4 u2 = *(const uint4*)(hxh + (size_t)s2 * DE + q * 8);
            uint4 u3 = *(const uint4*)(hxh + (size_t)s3 * DE + q * 8);
            float w0 = edge_w(e0 + adv), w1 = edge_w(e1 + adv);
            float w2 = edge_w(e2 + adv), w3 = edge_w(e3 + adv);
            wsum += (w0 + w1) + (w2 + w3);
            acc8pk(w0, u0, ah0, ah1, ah2, ah3);
            acc8pk(w1, u1, ah0, ah1, ah2, ah3);
            acc8pk(w2, u2, ah0, ah1, ah2, ah3);
            acc8pk(w3, u3, ah0, ah1, ah2, ah3);
        }
        for (; j < end; ++j) {
            int s0 = ssrc[j];
            float w0 = edge_w(as_[s0 * NH + hd] + adv);
            uint4 u0 = *(const uint4*)(hxh + (size_t)s0 * DE + q * 8);
            wsum += w0;
            acc8pk(w0, u0, ah0, ah1, ah2, ah3);
        }
        float inv = 1.f / wsum;
        float2 f0 = __half22float2(ah0), f1 = __half22float2(ah1);
        float2 f2 = __half22float2(ah2), f3 = __half22float2(ah3);
        p0.x = fmaf(inv, f0.x, p0.x); p0.y = fmaf(inv, f0.y, p0.y);
        p0.z = fmaf(inv, f1.x, p0.z); p0.w = fmaf(inv, f1.y, p0.w);
        p1.x = fmaf(inv, f2.x, p1.x); p1.y = fmaf(inv, f2.y, p1.y);
        p1.z = fmaf(inv, f3.x, p1.z); p1.w = fmaf(inv, f3.y, p1.w);
    }

    *(float4*)&sp[w][lane * 8]     = p0;
    *(float4*)&sp[w][lane * 8 + 4] = p1;
    __syncthreads();
    int t = threadIdx.x;
    {
        float s0 = sp[0][t] + sp[1][t] + sp[2][t] + sp[3][t];
        float s1 = sp[0][t + 256] + sp[1][t + 256] + sp[2][t + 256] + sp[3][t + 256];
        sp[0][t] = s0;
        sp[0][t + 256] = s1;
    }
    __syncthreads();
    int cn = nend - nbeg;
    #pragma unroll
    for (int half = 0; half < 2; ++half) {
        int ch = t + half * 256;
        int hd2 = ch >> 6;
        float acc = (float)cn * b2[ch];
        const float* pp = &sp[0][hd2 * 64];
        #pragma unroll 8
        for (int c = 0; c < 64; ++c)
            acc = fmaf(pp[c], W2[(size_t)c * 512 + ch], acc);   // coalesced: ch contiguous across threads
        g0[(size_t)g * CT + ch] = acc;
    }
}

// ---------------- MLP GEMM: fp16 W, 16x64 tiles, 128 threads, 1000 blocks ----------------
// thread = 1 row x 8 cols (one uint4 of W per k). grid (125, 8).
// FINAL fuses @fcW3 via 8-lane shfl reduce + atomicAdd.

template<bool FINAL>
__global__ __launch_bounds__(128) void tgemm_k(
        const float* __restrict__ A, const __half* __restrict__ Wh,
        const float* __restrict__ bias, float* __restrict__ Y,
        const float* __restrict__ W3, float* __restrict__ outp) {
    constexpr int K = 512, N = 512;
    __shared__ float As[64][17];
    int t = threadIdx.x;          // 0..127
    int row0 = blockIdx.x * 16;
    int col0 = blockIdx.y * 64;
    int r = t >> 3;               // 0..15
    int cg = t & 7;
    int c0 = cg * 8;
    float acc[8] = {0.f, 0.f, 0.f, 0.f, 0.f, 0.f, 0.f, 0.f};

    for (int kc = 0; kc < K; kc += 64) {
        if (kc) __syncthreads();
        {   // stage A tile [16 rows][64 k]: thread loads 8 floats of row r
            const float* ap = A + (size_t)(row0 + r) * K + kc + cg * 8;
            float4 v0 = *(const float4*)(ap);
            float4 v1 = *(const float4*)(ap + 4);
            As[cg * 8 + 0][r] = v0.x; As[cg * 8 + 1][r] = v0.y;
            As[cg * 8 + 2][r] = v0.z; As[cg * 8 + 3][r] = v0.w;
            As[cg * 8 + 4][r] = v1.x; As[cg * 8 + 5][r] = v1.y;
            As[cg * 8 + 6][r] = v1.z; As[cg * 8 + 7][r] = v1.w;
        }
        __syncthreads();
        const __half* wp = Wh + (size_t)kc * N + col0 + c0;
        #pragma unroll 8
        for (int k = 0; k < 64; ++k) {
            float a = As[k][r];
            uint4 u = *(const uint4*)(wp + (size_t)k * N);
            float f[8];
            unpack8(u, f);
            acc[0] = fmaf(a, f[0], acc[0]); acc[1] = fmaf(a, f[1], acc[1]);
            acc[2] = fmaf(a, f[2], acc[2]); acc[3] = fmaf(a, f[3], acc[3]);
            acc[4] = fmaf(a, f[4], acc[4]); acc[5] = fmaf(a, f[5], acc[5]);
            acc[6] = fmaf(a, f[6], acc[6]); acc[7] = fmaf(a, f[7], acc[7]);
        }
    }
    float4 bv0 = *(const float4*)(bias + col0 + c0);
    float4 bv1 = *(const float4*)(bias + col0 + c0 + 4);
    float o[8];
    o[0] = fmaxf(acc[0] + bv0.x, 0.f); o[1] = fmaxf(acc[1] + bv0.y, 0.f);
    o[2] = fmaxf(acc[2] + bv0.z, 0.f); o[3] = fmaxf(acc[3] + bv0.w, 0.f);
    o[4] = fmaxf(acc[4] + bv1.x, 0.f); o[5] = fmaxf(acc[5] + bv1.y, 0.f);
    o[6] = fmaxf(acc[6] + bv1.z, 0.f); o[7] = fmaxf(acc[7] + bv1.w, 0.f);
    if constexpr (!FINAL) {
        float* yp = Y + (size_t)(row0 + r) * N + col0 + c0;
        float4 s0 = {o[0], o[1], o[2], o[3]};
        float4 s1 = {o[4], o[5], o[6], o[7]};
        *(float4*)(yp)     = s0;
        *(float4*)(yp + 4) = s1;
    } else {
        float4 w30 = *(const float4*)(W3 + col0 + c0);
        float4 w31 = *(const float4*)(W3 + col0 + c0 + 4);
        float s = o[0] * w30.x + o[1] * w30.y + o[2] * w30.z + o[3] * w30.w
                + o[4] * w31.x + o[5] * w31.y + o[6] * w31.z + o[7] * w31.w;
        s += __shfl_xor(s, 1, 64);
        s += __shfl_xor(s, 2, 64);
        s += __shfl_xor(s, 4, 64);
        if (cg == 0) atomicAdd(&outp[row0 + r], s);
    }
}

// ---------------- launch ----------------

extern "C" void kernel_launch(void* const* d_in, const int* in_sizes, int n_in,
                              void* d_out, int out_size, void* d_ws, size_t ws_size,
                              hipStream_t stream) {
    const float* x     = (const float*)d_in[0];
    const int*   ei    = (const int*)d_in[1];
    const int*   batch = (const int*)d_in[2];
    const float* W1    = (const float*)d_in[3];
    const float* asrc1 = (const float*)d_in[4];
    const float* adst1 = (const float*)d_in[5];
    const float* b1    = (const float*)d_in[6];
    const float* W2    = (const float*)d_in[7];
    const float* asrc2 = (const float*)d_in[8];
    const float* adst2 = (const float*)d_in[9];
    const float* b2    = (const float*)d_in[10];
    const float* fcW1  = (const float*)d_in[11];
    const float* fcb1  = (const float*)d_in[12];
    const float* fcW2  = (const float*)d_in[13];
    const float* fcb2  = (const float*)d_in[14];
    const float* fcW3  = (const float*)d_in[15];
    const float* fcb3  = (const float*)d_in[16];
    float* outp = (float*)d_out;

    char* p = (char*)d_ws;
    auto take = [&](size_t bytes) {
        char* r = p;
        p += (bytes + 255) & ~(size_t)255;
        return r;
    };
    __half* aggx1h = (__half*)take((size_t)N_NODES * 256 * 2); // 25.6 MB fp16
    __half* hxh    = (__half*)take((size_t)N_NODES * DE * 2);  // 6.4 MB fp16
    __half* xh     = (__half*)take((size_t)N_NODES * NF * 2);  // 3.2 MB fp16
    float*  as_    = (float*)take((size_t)N_NODES * NH * 4);
    float*  ad_    = (float*)take((size_t)N_NODES * NH * 4);
    int*    ssrc   = (int*)take((size_t)(N_EDGES + N_NODES) * 4);
    int*    offv   = (int*)take((size_t)N_NODES * 4);
    int*    cntv   = (int*)take((size_t)N_NODES * 4);
    int*    cur    = (int*)take((size_t)N_NODES * 4);
    int*    total  = (int*)take(256);
    int*    goff   = (int*)take((size_t)(NG + 1) * 4);
    float*  B2s    = (float*)take(512 * 4);
    float*  B2d    = (float*)take(512 * 4);
    float*  U1     = (float*)take(256 * 64 * 4);
    __half* fw1h   = (__half*)take((size_t)DMLP * DMLP * 2);   // 512 KB fp16
    __half* fw2h   = (__half*)take((size_t)DMLP * DMLP * 2);   // 512 KB fp16
    float*  g0     = (float*)take((size_t)NG * DMLP * 4);
    float*  g1     = (float*)take((size_t)NG * DMLP * 4);

    // 1. all dependency-free prep (incl. out = fcb3, x->fp16, fcW->fp16 + L3 warm)
    setup_k<<<SB_A + SB_I + SB_U + SB_G + SB_B + SB_O + SB_X + SB_F, 256, 0, stream>>>(
        x, W1, asrc1, adst1, W2, asrc2, adst2, batch, fcb3, fcW1, fcW2,
        cntv, cur, total, U1, goff, B2s, B2d, as_, ad_, outp, xh, fw1h, fw2h);

    // 2-4. CSR build
    hist_k<<<(N_EDGES + 255) / 256, 256, 0, stream>>>(ei, cntv);
    alloc_off_k<<<(N_NODES + 255) / 256, 256, 0, stream>>>(cntv, offv, total);
    scatter_k<<<(N_EDGES + N_NODES + 255) / 256, 256, 0, stream>>>(ei, offv, cur, ssrc);

    // 5-6. layer 1: aggregate fp16 x per head (fp16 out, unroll 8); fused proj + alpha2
    agg1_k<<<(N_NODES + 3) / 4, 256, 0, stream>>>(xh, as_, ad_, ssrc, offv, cntv, aggx1h);
    proj1a_k<<<(N_NODES + 63) / 64, 256, 0, stream>>>(aggx1h, U1, b1, B2s, B2d, hxh, as_, ad_);

    // 7. layer 2: fused agg (fp16 gather, pk-fp16 accumulate, unroll 8) + pool + projection
    agg2gp_k<<<NG, 256, 0, stream>>>(hxh, as_, ad_, ssrc, offv, cntv, goff, W2, b2, g0);

    // 8-9. MLP head: fp16 W, 16x64 tiles, 1000 blocks (final projection fused into fc2)
    {
        dim3 grid(NG / 16, DMLP / 64);   // 125 x 8
        tgemm_k<false><<<grid, 128, 0, stream>>>(g0, fw1h, fcb1, g1, nullptr, nullptr);
        tgemm_k<true><<<grid, 128, 0, stream>>>(g1, fw2h, fcb2, nullptr, fcW3, outp);
    }
}

// Round 16
// 358.893 us; speedup vs baseline: 1.0388x; 1.0388x over previous
//
#include <hip/hip_runtime.h>
#include <hip/hip_fp16.h>

#define N_NODES   50000
#define N_EDGES   800000
#define NF        32
#define DE        64
#define NH        8
#define CT        512     // NH*DE
#define DMLP      512
#define NG        2000
#define NEGS      0.2f

// ---------------- helpers ----------------

__device__ inline float4 fma4(float a, float4 v, float4 c) {
    c.x = fmaf(a, v.x, c.x); c.y = fmaf(a, v.y, c.y);
    c.z = fmaf(a, v.z, c.z); c.w = fmaf(a, v.w, c.w);
    return c;
}

__device__ inline float edge_w(float e) {
    e = e > 0.f ? e : NEGS * e;
    return __expf(e);      // no max-subtraction: ratio Σw·v / Σw is invariant
}

__device__ inline unsigned packh2(float a, float b) {
    __half2 h = __floats2half2_rn(a, b);
    return *reinterpret_cast<unsigned*>(&h);
}
__device__ inline float2 uph2(unsigned u) {
    __half2 h = *reinterpret_cast<__half2*>(&u);
    return __half22float2(h);
}
__device__ inline void unpack8(uint4 u, float* f) {
    float2 a = uph2(u.x), b = uph2(u.y), c = uph2(u.z), d = uph2(u.w);
    f[0] = a.x; f[1] = a.y; f[2] = b.x; f[3] = b.y;
    f[4] = c.x; f[5] = c.y; f[6] = d.x; f[7] = d.y;
}

// ---------------- setup mega-kernel (all dependency-free prep) ----------------
// ranges: alpha1 | cnt/cur/total init | U1 | goffs | B2 | out=fcb3 | x->fp16 | fcW->fp16

#define SB_A 1563   // ceil(400000/256)
#define SB_I 196
#define SB_U 64
#define SB_G 196
#define SB_B 2
#define SB_O 8      // 2000/256
#define SB_X 782    // ceil(50000*32/8/256)
#define SB_F 256    // 2*512*512/8/256 (fcW1+fcW2 -> fp16; also warms L3)

__global__ __launch_bounds__(256) void setup_k(
        const float* __restrict__ x, const float* __restrict__ W1,
        const float* __restrict__ as1, const float* __restrict__ ad1,
        const float* __restrict__ W2, const float* __restrict__ as2,
        const float* __restrict__ ad2, const int* __restrict__ batch,
        const float* __restrict__ fcb3,
        const float* __restrict__ fcW1, const float* __restrict__ fcW2,
        int* __restrict__ cnt, int* __restrict__ cur, int* __restrict__ total,
        float* __restrict__ U1, int* __restrict__ goff,
        float* __restrict__ B2s, float* __restrict__ B2d,
        float* __restrict__ as_, float* __restrict__ ad_,
        float* __restrict__ outp, __half* __restrict__ xh,
        __half* __restrict__ fw1h, __half* __restrict__ fw2h) {
    int b = blockIdx.x;
    int tid = threadIdx.x;
    if (b < SB_A) {
        // layer-1 attention logits; B1 = W1·a computed per block into LDS
        __shared__ float bs[256], bd[256];
        {
            int c = tid >> 3, hd = tid & 7;
            const float* wr = W1 + c * 512 + hd * 64;
            const float* p1 = as1 + hd * 64;
            const float* p2 = ad1 + hd * 64;
            float s1 = 0.f, s2 = 0.f;
            #pragma unroll 8
            for (int f = 0; f < 64; ++f) { float w = wr[f]; s1 += w * p1[f]; s2 += w * p2[f]; }
            bs[tid] = s1; bd[tid] = s2;
        }
        __syncthreads();
        int gid = b * 256 + tid;
        if (gid < N_NODES * NH) {
            int n = gid >> 3, hd = gid & 7;
            const float4* xp = (const float4*)(x + (size_t)n * NF);
            float s1 = 0.f, s2 = 0.f;
            #pragma unroll
            for (int qq = 0; qq < NF / 4; ++qq) {
                float4 v = xp[qq];
                int b0 = qq * 32 + hd;
                s1 += v.x * bs[b0] + v.y * bs[b0 + 8] + v.z * bs[b0 + 16] + v.w * bs[b0 + 24];
                s2 += v.x * bd[b0] + v.y * bd[b0 + 8] + v.z * bd[b0 + 16] + v.w * bd[b0 + 24];
            }
            as_[gid] = s1;
            ad_[gid] = s2;
        }
    } else if (b < SB_A + SB_I) {
        int i = (b - SB_A) * 256 + tid;
        if (i < N_NODES) { cnt[i] = 1; cur[i] = 0; }   // 1 = self-loop
        if (i == 0) total[0] = 0;
    } else if (b < SB_A + SB_I + SB_U) {
        int i = (b - SB_A - SB_I) * 256 + tid;         // U1[hd*32+c][f] = W1[c][hd*64+f]/8
        int k = i >> 6, f = i & 63;
        int hd = k >> 5, c = k & 31;
        U1[i] = W1[c * 512 + hd * 64 + f] * 0.125f;
    } else if (b < SB_A + SB_I + SB_U + SB_G) {
        int i = (b - SB_A - SB_I - SB_U) * 256 + tid;
        if (i < N_NODES) {
            int bb = batch[i];
            if (i == 0) {
                for (int g = 0; g <= bb; ++g) goff[g] = 0;
            } else {
                int pb = batch[i - 1];
                for (int g = pb + 1; g <= bb; ++g) goff[g] = i;
            }
            if (i == N_NODES - 1) {
                for (int g = bb + 1; g <= NG; ++g) goff[g] = N_NODES;
            }
        }
    } else if (b < SB_A + SB_I + SB_U + SB_G + SB_B) {
        int i = (b - SB_A - SB_I - SB_U - SB_G) * 256 + tid;   // < 512
        int c = i >> 3, hd = i & 7;
        const float* wr = W2 + c * 512 + hd * 64;
        const float* p1 = as2 + hd * 64;
        const float* p2 = ad2 + hd * 64;
        float s1 = 0.f, s2 = 0.f;
        #pragma unroll 8
        for (int f = 0; f < 64; ++f) { float w = wr[f]; s1 += w * p1[f]; s2 += w * p2[f]; }
        B2s[i] = s1; B2d[i] = s2;
    } else if (b < SB_A + SB_I + SB_U + SB_G + SB_B + SB_O) {
        int i = (b - SB_A - SB_I - SB_U - SB_G - SB_B) * 256 + tid;
        if (i < NG) outp[i] = fcb3[0];
    } else if (b < SB_A + SB_I + SB_U + SB_G + SB_B + SB_O + SB_X) {
        // x -> fp16 (8 floats per thread)
        int i = (b - SB_A - SB_I - SB_U - SB_G - SB_B - SB_O) * 256 + tid;
        if (i < N_NODES * NF / 8) {
            const float4* src = (const float4*)x + (size_t)i * 2;
            float4 v0 = src[0], v1 = src[1];
            uint4 u;
            u.x = packh2(v0.x, v0.y); u.y = packh2(v0.z, v0.w);
            u.z = packh2(v1.x, v1.y); u.w = packh2(v1.z, v1.w);
            *(uint4*)(xh + (size_t)i * 8) = u;
        }
    } else {
        // fcW1/fcW2 -> fp16 (8 floats per thread); also pre-warms L3 for the MLP
        int i = (b - SB_A - SB_I - SB_U - SB_G - SB_B - SB_O - SB_X) * 256 + tid;
        const float* src = (i < 32768) ? fcW1 : fcW2;
        __half* dst = (i < 32768) ? fw1h : fw2h;
        int off = (i & 32767) * 8;
        const float4* s4 = (const float4*)(src + off);
        float4 v0 = s4[0], v1 = s4[1];
        uint4 u;
        u.x = packh2(v0.x, v0.y); u.y = packh2(v0.z, v0.w);
        u.z = packh2(v1.x, v1.y); u.w = packh2(v1.z, v1.w);
        *(uint4*)(dst + off) = u;
    }
}

// ---------------- CSR build ----------------

__global__ void hist_k(const int* __restrict__ ei, int* __restrict__ cnt) {
    int e = blockIdx.x * 256 + threadIdx.x;
    if (e < N_EDGES) atomicAdd(&cnt[ei[N_EDGES + e]], 1);   // row 1 = dst
}

__global__ void alloc_off_k(const int* __restrict__ cnt, int* __restrict__ off,
                            int* __restrict__ total) {
    int i = blockIdx.x * 256 + threadIdx.x;
    if (i < N_NODES) off[i] = atomicAdd(total, cnt[i]);
}

__global__ void scatter_k(const int* __restrict__ ei, const int* __restrict__ off,
                          int* __restrict__ cur, int* __restrict__ ssrc) {
    int e = blockIdx.x * 256 + threadIdx.x;
    if (e < N_EDGES) {
        int s = ei[e];
        int d = ei[N_EDGES + e];
        int p = off[d] + atomicAdd(&cur[d], 1);
        ssrc[p] = s;
    } else if (e < N_EDGES + N_NODES) {
        int i = e - N_EDGES;                    // self loop
        int p = off[i] + atomicAdd(&cur[i], 1);
        ssrc[p] = i;
    }
}

// ---------------- layer-1 aggregation over fp16 x (wave per node, unroll 4) ----------------

__global__ __launch_bounds__(256) void agg1_k(
        const __half* __restrict__ xh, const float* __restrict__ as_,
        const float* __restrict__ ad_, const int* __restrict__ ssrc,
        const int* __restrict__ off, const int* __restrict__ cnt,
        __half* __restrict__ aggx1h) {
    int wv = __builtin_amdgcn_readfirstlane(blockIdx.x * 4 + (threadIdx.x >> 6));
    if (wv >= N_NODES) return;
    int lane = threadIdx.x & 63;
    int hd = lane >> 3, q = lane & 7;
    int beg = off[wv], end = beg + cnt[wv];
    float adv = ad_[wv * NH + hd];

    float4 acc = {0.f, 0.f, 0.f, 0.f};
    float wsum = 0.f;
    int j = beg;
    for (; j + 4 <= end; j += 4) {
        int s0 = ssrc[j], s1 = ssrc[j + 1], s2 = ssrc[j + 2], s3 = ssrc[j + 3];
        float e0 = as_[s0 * NH + hd], e1 = as_[s1 * NH + hd];
        float e2 = as_[s2 * NH + hd], e3 = as_[s3 * NH + hd];
        uint2 u0 = *(const uint2*)(xh + (size_t)s0 * NF + q * 4);
        uint2 u1 = *(const uint2*)(xh + (size_t)s1 * NF + q * 4);
        uint2 u2 = *(const uint2*)(xh + (size_t)s2 * NF + q * 4);
        uint2 u3 = *(const uint2*)(xh + (size_t)s3 * NF + q * 4);
        float w0 = edge_w(e0 + adv), w1 = edge_w(e1 + adv);
        float w2 = edge_w(e2 + adv), w3 = edge_w(e3 + adv);
        wsum += (w0 + w1) + (w2 + w3);
        float2 a01, a23;
        a01 = uph2(u0.x); a23 = uph2(u0.y);
        acc.x = fmaf(w0, a01.x, acc.x); acc.y = fmaf(w0, a01.y, acc.y);
        acc.z = fmaf(w0, a23.x, acc.z); acc.w = fmaf(w0, a23.y, acc.w);
        a01 = uph2(u1.x); a23 = uph2(u1.y);
        acc.x = fmaf(w1, a01.x, acc.x); acc.y = fmaf(w1, a01.y, acc.y);
        acc.z = fmaf(w1, a23.x, acc.z); acc.w = fmaf(w1, a23.y, acc.w);
        a01 = uph2(u2.x); a23 = uph2(u2.y);
        acc.x = fmaf(w2, a01.x, acc.x); acc.y = fmaf(w2, a01.y, acc.y);
        acc.z = fmaf(w2, a23.x, acc.z); acc.w = fmaf(w2, a23.y, acc.w);
        a01 = uph2(u3.x); a23 = uph2(u3.y);
        acc.x = fmaf(w3, a01.x, acc.x); acc.y = fmaf(w3, a01.y, acc.y);
        acc.z = fmaf(w3, a23.x, acc.z); acc.w = fmaf(w3, a23.y, acc.w);
    }
    for (; j < end; ++j) {
        int s0 = ssrc[j];
        float w0 = edge_w(as_[s0 * NH + hd] + adv);
        uint2 u0 = *(const uint2*)(xh + (size_t)s0 * NF + q * 4);
        wsum += w0;
        float2 a01 = uph2(u0.x), a23 = uph2(u0.y);
        acc.x = fmaf(w0, a01.x, acc.x); acc.y = fmaf(w0, a01.y, acc.y);
        acc.z = fmaf(w0, a23.x, acc.z); acc.w = fmaf(w0, a23.y, acc.w);
    }
    float inv = 1.f / wsum;
    uint2 st;
    st.x = packh2(acc.x * inv, acc.y * inv);
    st.y = packh2(acc.z * inv, acc.w * inv);
    *(uint2*)(aggx1h + (size_t)wv * 256 + lane * 4) = st;   // [hd*32 + q*4] == lane*4
}

// ---------------- proj1 + alpha2 fused: hxh = fp16(aggx1h @ U1 + b1); as_/ad_ from fp32 ----

__global__ __launch_bounds__(256) void proj1a_k(
        const __half* __restrict__ Ah, const float* __restrict__ U1,
        const float* __restrict__ b1, const float* __restrict__ B2s,
        const float* __restrict__ B2d, __half* __restrict__ hxh,
        float* __restrict__ as_, float* __restrict__ ad_) {
    __shared__ float As[64][64];
    __shared__ float bs2[512], bd2[512];
    int t = threadIdx.x;
    int row0 = blockIdx.x * 64;
    for (int i = t; i < 512; i += 256) { bs2[i] = B2s[i]; bd2[i] = B2d[i]; }
    int rr = t & 63;
    int kb = (t >> 6) * 16;
    int r0 = (t >> 4) * 4;
    int c0 = (t & 15) * 4;
    float acc[4][4];
    #pragma unroll
    for (int i = 0; i < 4; ++i)
        #pragma unroll
        for (int j = 0; j < 4; ++j) acc[i][j] = 0.f;

    for (int kc = 0; kc < 256; kc += 64) {
        __syncthreads();
        {
            int grow = row0 + rr;
            const __half* ap = Ah + (size_t)grow * 256 + kc + kb;
            uint4 u0 = {0, 0, 0, 0}, u1 = {0, 0, 0, 0};
            if (grow < N_NODES) {
                u0 = *(const uint4*)(ap);
                u1 = *(const uint4*)(ap + 8);
            }
            float f[16];
            unpack8(u0, f);
            unpack8(u1, f + 8);
            #pragma unroll
            for (int i = 0; i < 16; ++i) As[kb + i][rr] = f[i];
        }
        __syncthreads();
        const float* wp = U1 + (size_t)kc * 64 + c0;
        #pragma unroll 4
        for (int k = 0; k < 64; ++k) {
            float4 a = *(const float4*)&As[k][r0];
            float4 w = *(const float4*)(wp + k * 64);
            acc[0][0] = fmaf(a.x, w.x, acc[0][0]); acc[0][1] = fmaf(a.x, w.y, acc[0][1]);
            acc[0][2] = fmaf(a.x, w.z, acc[0][2]); acc[0][3] = fmaf(a.x, w.w, acc[0][3]);
            acc[1][0] = fmaf(a.y, w.x, acc[1][0]); acc[1][1] = fmaf(a.y, w.y, acc[1][1]);
            acc[1][2] = fmaf(a.y, w.z, acc[1][2]); acc[1][3] = fmaf(a.y, w.w, acc[1][3]);
            acc[2][0] = fmaf(a.z, w.x, acc[2][0]); acc[2][1] = fmaf(a.z, w.y, acc[2][1]);
            acc[2][2] = fmaf(a.z, w.z, acc[2][2]); acc[2][3] = fmaf(a.z, w.w, acc[2][3]);
            acc[3][0] = fmaf(a.w, w.x, acc[3][0]); acc[3][1] = fmaf(a.w, w.y, acc[3][1]);
            acc[3][2] = fmaf(a.w, w.z, acc[3][2]); acc[3][3] = fmaf(a.w, w.w, acc[3][3]);
        }
    }
    __syncthreads();
    // write hx tile (with bias) into As as [row][col]
    float4 bv = *(const float4*)(b1 + c0);
    #pragma unroll
    for (int i = 0; i < 4; ++i) {
        As[r0 + i][c0 + 0] = acc[i][0] + bv.x;
        As[r0 + i][c0 + 1] = acc[i][1] + bv.y;
        As[r0 + i][c0 + 2] = acc[i][2] + bv.z;
        As[r0 + i][c0 + 3] = acc[i][3] + bv.w;
    }
    __syncthreads();
    // epilogue: thread t -> row = t>>2, col-slice sub = t&3 (cols sub*16..+16)
    int row = t >> 2, sub = t & 3;
    int grow = row0 + row;
    float ps[8], pd[8];
    #pragma unroll
    for (int hd = 0; hd < 8; ++hd) { ps[hd] = 0.f; pd[hd] = 0.f; }
    #pragma unroll 4
    for (int c2 = 0; c2 < 16; ++c2) {
        int c = sub * 16 + c2;
        float v = As[row][c];
        #pragma unroll
        for (int hd = 0; hd < 8; ++hd) {
            ps[hd] = fmaf(v, bs2[c * 8 + hd], ps[hd]);
            pd[hd] = fmaf(v, bd2[c * 8 + hd], pd[hd]);
        }
    }
    #pragma unroll
    for (int d = 1; d <= 2; d <<= 1) {
        #pragma unroll
        for (int hd = 0; hd < 8; ++hd) {
            ps[hd] += __shfl_xor(ps[hd], d, 64);
            pd[hd] += __shfl_xor(pd[hd], d, 64);
        }
    }
    if (grow < N_NODES) {
        int h0 = sub * 2;
        as_[grow * 8 + h0]     = ps[h0];
        as_[grow * 8 + h0 + 1] = ps[h0 + 1];
        ad_[grow * 8 + h0]     = pd[h0];
        ad_[grow * 8 + h0 + 1] = pd[h0 + 1];
        // fp16 store of cols sub*16..+16 (logits above were from fp32 - exact)
        const float* r = &As[row][sub * 16];
        uint4 u0, u1;
        u0.x = packh2(r[0],  r[1]);  u0.y = packh2(r[2],  r[3]);
        u0.z = packh2(r[4],  r[5]);  u0.w = packh2(r[6],  r[7]);
        u1.x = packh2(r[8],  r[9]);  u1.y = packh2(r[10], r[11]);
        u1.z = packh2(r[12], r[13]); u1.w = packh2(r[14], r[15]);
        *(uint4*)(hxh + (size_t)grow * 64 + sub * 16)     = u0;
        *(uint4*)(hxh + (size_t)grow * 64 + sub * 16 + 8) = u1;
    }
}

// ---------------- layer-2 agg (fp16 gather, packed fp16 accumulate) + pool + projection ----
// one block (4 waves) per graph; lane owns channels lane*8..+8 (head = lane>>3).
// fp16 accumulation is overflow-safe here: layer-2 logits sigma ~0.2 -> w in ~[0.5,2].

__device__ inline void acc8pk(float w, uint4 u, __half2& a0, __half2& a1,
                              __half2& a2, __half2& a3) {
    __half2 wh = __float2half2_rn(w);
    union { uint4 u4; __half2 h[4]; } c;
    c.u4 = u;
    a0 = __hfma2(wh, c.h[0], a0);
    a1 = __hfma2(wh, c.h[1], a1);
    a2 = __hfma2(wh, c.h[2], a2);
    a3 = __hfma2(wh, c.h[3], a3);
}

__global__ __launch_bounds__(256) void agg2gp_k(
        const __half* __restrict__ hxh, const float* __restrict__ as_,
        const float* __restrict__ ad_, const int* __restrict__ ssrc,
        const int* __restrict__ off, const int* __restrict__ cnt,
        const int* __restrict__ goff, const float* __restrict__ W2,
        const float* __restrict__ b2, float* __restrict__ g0) {
    int g = blockIdx.x;
    int w = threadIdx.x >> 6;
    int lane = threadIdx.x & 63;
    int hd = lane >> 3, q = lane & 7;
    int nbeg = goff[g], nend = goff[g + 1];

    __shared__ float sp[4][512];

    float4 p0 = {0.f, 0.f, 0.f, 0.f}, p1 = {0.f, 0.f, 0.f, 0.f};

    for (int nd0 = nbeg + w; nd0 < nend; nd0 += 4) {
        int nd = __builtin_amdgcn_readfirstlane(nd0);
        int beg = off[nd], end = beg + cnt[nd];
        float adv = ad_[nd * NH + hd];

        __half2 z = __float2half2_rn(0.f);
        __half2 ah0 = z, ah1 = z, ah2 = z, ah3 = z;
        float wsum = 0.f;
        int j = beg;
        for (; j + 4 <= end; j += 4) {
            int s0 = ssrc[j], s1 = ssrc[j + 1], s2 = ssrc[j + 2], s3 = ssrc[j + 3];
            float e0 = as_[s0 * NH + hd], e1 = as_[s1 * NH + hd];
            float e2 = as_[s2 * NH + hd], e3 = as_[s3 * NH + hd];
            uint4 u0 = *(const uint4*)(hxh + (size_t)s0 * DE + q * 8);
            uint4 u1 = *(const uint4*)(hxh + (size_t)s1 * DE + q * 8);
            uint4 u2 = *(const uint4*)(hxh + (size_t)s2 * DE + q * 8);
            uint4 u3 = *(const uint4*)(hxh + (size_t)s3 * DE + q * 8);
            float w0 = edge_w(e0 + adv), w1 = edge_w(e1 + adv);
            float w2 = edge_w(e2 + adv), w3 = edge_w(e3 + adv);
            wsum += (w0 + w1) + (w2 + w3);
            acc8pk(w0, u0, ah0, ah1, ah2, ah3);
            acc8pk(w1, u1, ah0, ah1, ah2, ah3);
            acc8pk(w2, u2, ah0, ah1, ah2, ah3);
            acc8pk(w3, u3, ah0, ah1, ah2, ah3);
        }
        for (; j < end; ++j) {
            int s0 = ssrc[j];
            float w0 = edge_w(as_[s0 * NH + hd] + adv);
            uint4 u0 = *(const uint4*)(hxh + (size_t)s0 * DE + q * 8);
            wsum += w0;
            acc8pk(w0, u0, ah0, ah1, ah2, ah3);
        }
        float inv = 1.f / wsum;
        float2 f0 = __half22float2(ah0), f1 = __half22float2(ah1);
        float2 f2 = __half22float2(ah2), f3 = __half22float2(ah3);
        p0.x = fmaf(inv, f0.x, p0.x); p0.y = fmaf(inv, f0.y, p0.y);
        p0.z = fmaf(inv, f1.x, p0.z); p0.w = fmaf(inv, f1.y, p0.w);
        p1.x = fmaf(inv, f2.x, p1.x); p1.y = fmaf(inv, f2.y, p1.y);
        p1.z = fmaf(inv, f3.x, p1.z); p1.w = fmaf(inv, f3.y, p1.w);
    }

    *(float4*)&sp[w][lane * 8]     = p0;
    *(float4*)&sp[w][lane * 8 + 4] = p1;
    __syncthreads();
    int t = threadIdx.x;
    {
        float s0 = sp[0][t] + sp[1][t] + sp[2][t] + sp[3][t];
        float s1 = sp[0][t + 256] + sp[1][t + 256] + sp[2][t + 256] + sp[3][t + 256];
        sp[0][t] = s0;
        sp[0][t + 256] = s1;
    }
    __syncthreads();
    int cn = nend - nbeg;
    #pragma unroll
    for (int half = 0; half < 2; ++half) {
        int ch = t + half * 256;
        int hd2 = ch >> 6;
        float acc = (float)cn * b2[ch];
        const float* pp = &sp[0][hd2 * 64];
        #pragma unroll 8
        for (int c = 0; c < 64; ++c)
            acc = fmaf(pp[c], W2[(size_t)c * 512 + ch], acc);   // coalesced: ch contiguous across threads
        g0[(size_t)g * CT + ch] = acc;
    }
}

// ---------------- MLP GEMM: fp16 W, 16x64 tiles, 128 threads, 1000 blocks ----------------
// thread = 1 row x 8 cols (one uint4 of W per k). grid (125, 8).
// FINAL fuses @fcW3 via 8-lane shfl reduce + atomicAdd.

template<bool FINAL>
__global__ __launch_bounds__(128) void tgemm_k(
        const float* __restrict__ A, const __half* __restrict__ Wh,
        const float* __restrict__ bias, float* __restrict__ Y,
        const float* __restrict__ W3, float* __restrict__ outp) {
    constexpr int K = 512, N = 512;
    __shared__ float As[64][17];
    int t = threadIdx.x;          // 0..127
    int row0 = blockIdx.x * 16;
    int col0 = blockIdx.y * 64;
    int r = t >> 3;               // 0..15
    int cg = t & 7;
    int c0 = cg * 8;
    float acc[8] = {0.f, 0.f, 0.f, 0.f, 0.f, 0.f, 0.f, 0.f};

    for (int kc = 0; kc < K; kc += 64) {
        if (kc) __syncthreads();
        {   // stage A tile [16 rows][64 k]: thread loads 8 floats of row r
            const float* ap = A + (size_t)(row0 + r) * K + kc + cg * 8;
            float4 v0 = *(const float4*)(ap);
            float4 v1 = *(const float4*)(ap + 4);
            As[cg * 8 + 0][r] = v0.x; As[cg * 8 + 1][r] = v0.y;
            As[cg * 8 + 2][r] = v0.z; As[cg * 8 + 3][r] = v0.w;
            As[cg * 8 + 4][r] = v1.x; As[cg * 8 + 5][r] = v1.y;
            As[cg * 8 + 6][r] = v1.z; As[cg * 8 + 7][r] = v1.w;
        }
        __syncthreads();
        const __half* wp = Wh + (size_t)kc * N + col0 + c0;
        #pragma unroll 8
        for (int k = 0; k < 64; ++k) {
            float a = As[k][r];
            uint4 u = *(const uint4*)(wp + (size_t)k * N);
            float f[8];
            unpack8(u, f);
            acc[0] = fmaf(a, f[0], acc[0]); acc[1] = fmaf(a, f[1], acc[1]);
            acc[2] = fmaf(a, f[2], acc[2]); acc[3] = fmaf(a, f[3], acc[3]);
            acc[4] = fmaf(a, f[4], acc[4]); acc[5] = fmaf(a, f[5], acc[5]);
            acc[6] = fmaf(a, f[6], acc[6]); acc[7] = fmaf(a, f[7], acc[7]);
        }
    }
    float4 bv0 = *(const float4*)(bias + col0 + c0);
    float4 bv1 = *(const float4*)(bias + col0 + c0 + 4);
    float o[8];
    o[0] = fmaxf(acc[0] + bv0.x, 0.f); o[1] = fmaxf(acc[1] + bv0.y, 0.f);
    o[2] = fmaxf(acc[2] + bv0.z, 0.f); o[3] = fmaxf(acc[3] + bv0.w, 0.f);
    o[4] = fmaxf(acc[4] + bv1.x, 0.f); o[5] = fmaxf(acc[5] + bv1.y, 0.f);
    o[6] = fmaxf(acc[6] + bv1.z, 0.f); o[7] = fmaxf(acc[7] + bv1.w, 0.f);
    if constexpr (!FINAL) {
        float* yp = Y + (size_t)(row0 + r) * N + col0 + c0;
        float4 s0 = {o[0], o[1], o[2], o[3]};
        float4 s1 = {o[4], o[5], o[6], o[7]};
        *(float4*)(yp)     = s0;
        *(float4*)(yp + 4) = s1;
    } else {
        float4 w30 = *(const float4*)(W3 + col0 + c0);
        float4 w31 = *(const float4*)(W3 + col0 + c0 + 4);
        float s = o[0] * w30.x + o[1] * w30.y + o[2] * w30.z + o[3] * w30.w
                + o[4] * w31.x + o[5] * w31.y + o[6] * w31.z + o[7] * w31.w;
        s += __shfl_xor(s, 1, 64);
        s += __shfl_xor(s, 2, 64);
        s += __shfl_xor(s, 4, 64);
        if (cg == 0) atomicAdd(&outp[row0 + r], s);
    }
}

// ---------------- launch ----------------

extern "C" void kernel_launch(void* const* d_in, const int* in_sizes, int n_in,
                              void* d_out, int out_size, void* d_ws, size_t ws_size,
                              hipStream_t stream) {
    const float* x     = (const float*)d_in[0];
    const int*   ei    = (const int*)d_in[1];
    const int*   batch = (const int*)d_in[2];
    const float* W1    = (const float*)d_in[3];
    const float* asrc1 = (const float*)d_in[4];
    const float* adst1 = (const float*)d_in[5];
    const float* b1    = (const float*)d_in[6];
    const float* W2    = (const float*)d_in[7];
    const float* asrc2 = (const float*)d_in[8];
    const float* adst2 = (const float*)d_in[9];
    const float* b2    = (const float*)d_in[10];
    const float* fcW1  = (const float*)d_in[11];
    const float* fcb1  = (const float*)d_in[12];
    const float* fcW2  = (const float*)d_in[13];
    const float* fcb2  = (const float*)d_in[14];
    const float* fcW3  = (const float*)d_in[15];
    const float* fcb3  = (const float*)d_in[16];
    float* outp = (float*)d_out;

    char* p = (char*)d_ws;
    auto take = [&](size_t bytes) {
        char* r = p;
        p += (bytes + 255) & ~(size_t)255;
        return r;
    };
    __half* aggx1h = (__half*)take((size_t)N_NODES * 256 * 2); // 25.6 MB fp16
    __half* hxh    = (__half*)take((size_t)N_NODES * DE * 2);  // 6.4 MB fp16
    __half* xh     = (__half*)take((size_t)N_NODES * NF * 2);  // 3.2 MB fp16
    float*  as_    = (float*)take((size_t)N_NODES * NH * 4);
    float*  ad_    = (float*)take((size_t)N_NODES * NH * 4);
    int*    ssrc   = (int*)take((size_t)(N_EDGES + N_NODES) * 4);
    int*    offv   = (int*)take((size_t)N_NODES * 4);
    int*    cntv   = (int*)take((size_t)N_NODES * 4);
    int*    cur    = (int*)take((size_t)N_NODES * 4);
    int*    total  = (int*)take(256);
    int*    goff   = (int*)take((size_t)(NG + 1) * 4);
    float*  B2s    = (float*)take(512 * 4);
    float*  B2d    = (float*)take(512 * 4);
    float*  U1     = (float*)take(256 * 64 * 4);
    __half* fw1h   = (__half*)take((size_t)DMLP * DMLP * 2);   // 512 KB fp16
    __half* fw2h   = (__half*)take((size_t)DMLP * DMLP * 2);   // 512 KB fp16
    float*  g0     = (float*)take((size_t)NG * DMLP * 4);
    float*  g1     = (float*)take((size_t)NG * DMLP * 4);

    // 1. all dependency-free prep (incl. out = fcb3, x->fp16, fcW->fp16 + L3 warm)
    setup_k<<<SB_A + SB_I + SB_U + SB_G + SB_B + SB_O + SB_X + SB_F, 256, 0, stream>>>(
        x, W1, asrc1, adst1, W2, asrc2, adst2, batch, fcb3, fcW1, fcW2,
        cntv, cur, total, U1, goff, B2s, B2d, as_, ad_, outp, xh, fw1h, fw2h);

    // 2-4. CSR build
    hist_k<<<(N_EDGES + 255) / 256, 256, 0, stream>>>(ei, cntv);
    alloc_off_k<<<(N_NODES + 255) / 256, 256, 0, stream>>>(cntv, offv, total);
    scatter_k<<<(N_EDGES + N_NODES + 255) / 256, 256, 0, stream>>>(ei, offv, cur, ssrc);

    // 5-6. layer 1: aggregate fp16 x per head (fp16 out); fused projection + alpha2
    agg1_k<<<(N_NODES + 3) / 4, 256, 0, stream>>>(xh, as_, ad_, ssrc, offv, cntv, aggx1h);
    proj1a_k<<<(N_NODES + 63) / 64, 256, 0, stream>>>(aggx1h, U1, b1, B2s, B2d, hxh, as_, ad_);

    // 7. layer 2: fused agg (fp16 gather, pk-fp16 accumulate) + pool + projection
    agg2gp_k<<<NG, 256, 0, stream>>>(hxh, as_, ad_, ssrc, offv, cntv, goff, W2, b2, g0);

    // 8-9. MLP head: fp16 W, 16x64 tiles, 1000 blocks (final projection fused into fc2)
    {
        dim3 grid(NG / 16, DMLP / 64);   // 125 x 8
        tgemm_k<false><<<grid, 128, 0, stream>>>(g0, fw1h, fcb1, g1, nullptr, nullptr);
        tgemm_k<true><<<grid, 128, 0, stream>>>(g1, fw2h, fcb2, nullptr, fcW3, outp);
    }
}

// Round 17
// 356.589 us; speedup vs baseline: 1.0455x; 1.0065x over previous
//
#include <hip/hip_runtime.h>
#include <hip/hip_fp16.h>

#define N_NODES   50000
#define N_EDGES   800000
#define NF        32
#define DE        64
#define NH        8
#define CT        512     // NH*DE
#define DMLP      512
#define NG        2000
#define NEGS      0.2f

// ---------------- helpers ----------------

__device__ inline float4 fma4(float a, float4 v, float4 c) {
    c.x = fmaf(a, v.x, c.x); c.y = fmaf(a, v.y, c.y);
    c.z = fmaf(a, v.z, c.z); c.w = fmaf(a, v.w, c.w);
    return c;
}

__device__ inline float edge_w(float e) {
    e = e > 0.f ? e : NEGS * e;
    return __expf(e);      // no max-subtraction: ratio Σw·v / Σw is invariant
}

__device__ inline unsigned packh2(float a, float b) {
    __half2 h = __floats2half2_rn(a, b);
    return *reinterpret_cast<unsigned*>(&h);
}
__device__ inline float2 uph2(unsigned u) {
    __half2 h = *reinterpret_cast<__half2*>(&u);
    return __half22float2(h);
}
__device__ inline void unpack8(uint4 u, float* f) {
    float2 a = uph2(u.x), b = uph2(u.y), c = uph2(u.z), d = uph2(u.w);
    f[0] = a.x; f[1] = a.y; f[2] = b.x; f[3] = b.y;
    f[4] = c.x; f[5] = c.y; f[6] = d.x; f[7] = d.y;
}

// ---------------- setup mega-kernel (all dependency-free prep) ----------------
// ranges: alpha1 | cur/total init | U1 | goffs | B2 | out=fcb3 | x->fp16 | fcW->fp16 | hist
// cnt[] is zeroed by a preceding hipMemsetAsync; hist blocks atomically build the
// edge histogram (self-loop handled as +1 in alloc_off / agg kernels).

#define SB_A 1563   // ceil(400000/256)
#define SB_I 196
#define SB_U 64
#define SB_G 196
#define SB_B 2
#define SB_O 8      // 2000/256
#define SB_X 782    // ceil(50000*32/8/256)
#define SB_F 256    // 2*512*512/8/256 (fcW1+fcW2 -> fp16; also warms L3)
#define SB_H 3125   // ceil(800000/256) edge histogram

__global__ __launch_bounds__(256) void setup_k(
        const float* __restrict__ x, const float* __restrict__ W1,
        const float* __restrict__ as1, const float* __restrict__ ad1,
        const float* __restrict__ W2, const float* __restrict__ as2,
        const float* __restrict__ ad2, const int* __restrict__ batch,
        const float* __restrict__ fcb3,
        const float* __restrict__ fcW1, const float* __restrict__ fcW2,
        const int* __restrict__ ei,
        int* __restrict__ cnt, int* __restrict__ cur, int* __restrict__ total,
        float* __restrict__ U1, int* __restrict__ goff,
        float* __restrict__ B2s, float* __restrict__ B2d,
        float* __restrict__ as_, float* __restrict__ ad_,
        float* __restrict__ outp, __half* __restrict__ xh,
        __half* __restrict__ fw1h, __half* __restrict__ fw2h) {
    int b = blockIdx.x;
    int tid = threadIdx.x;
    if (b < SB_A) {
        // layer-1 attention logits; B1 = W1·a computed per block into LDS
        __shared__ float bs[256], bd[256];
        {
            int c = tid >> 3, hd = tid & 7;
            const float* wr = W1 + c * 512 + hd * 64;
            const float* p1 = as1 + hd * 64;
            const float* p2 = ad1 + hd * 64;
            float s1 = 0.f, s2 = 0.f;
            #pragma unroll 8
            for (int f = 0; f < 64; ++f) { float w = wr[f]; s1 += w * p1[f]; s2 += w * p2[f]; }
            bs[tid] = s1; bd[tid] = s2;
        }
        __syncthreads();
        int gid = b * 256 + tid;
        if (gid < N_NODES * NH) {
            int n = gid >> 3, hd = gid & 7;
            const float4* xp = (const float4*)(x + (size_t)n * NF);
            float s1 = 0.f, s2 = 0.f;
            #pragma unroll
            for (int qq = 0; qq < NF / 4; ++qq) {
                float4 v = xp[qq];
                int b0 = qq * 32 + hd;
                s1 += v.x * bs[b0] + v.y * bs[b0 + 8] + v.z * bs[b0 + 16] + v.w * bs[b0 + 24];
                s2 += v.x * bd[b0] + v.y * bd[b0 + 8] + v.z * bd[b0 + 16] + v.w * bd[b0 + 24];
            }
            as_[gid] = s1;
            ad_[gid] = s2;
        }
    } else if (b < SB_A + SB_I) {
        int i = (b - SB_A) * 256 + tid;
        if (i < N_NODES) cur[i] = 0;
        if (i == 0) total[0] = 0;
    } else if (b < SB_A + SB_I + SB_U) {
        int i = (b - SB_A - SB_I) * 256 + tid;         // U1[hd*32+c][f] = W1[c][hd*64+f]/8
        int k = i >> 6, f = i & 63;
        int hd = k >> 5, c = k & 31;
        U1[i] = W1[c * 512 + hd * 64 + f] * 0.125f;
    } else if (b < SB_A + SB_I + SB_U + SB_G) {
        int i = (b - SB_A - SB_I - SB_U) * 256 + tid;
        if (i < N_NODES) {
            int bb = batch[i];
            if (i == 0) {
                for (int g = 0; g <= bb; ++g) goff[g] = 0;
            } else {
                int pb = batch[i - 1];
                for (int g = pb + 1; g <= bb; ++g) goff[g] = i;
            }
            if (i == N_NODES - 1) {
                for (int g = bb + 1; g <= NG; ++g) goff[g] = N_NODES;
            }
        }
    } else if (b < SB_A + SB_I + SB_U + SB_G + SB_B) {
        int i = (b - SB_A - SB_I - SB_U - SB_G) * 256 + tid;   // < 512
        int c = i >> 3, hd = i & 7;
        const float* wr = W2 + c * 512 + hd * 64;
        const float* p1 = as2 + hd * 64;
        const float* p2 = ad2 + hd * 64;
        float s1 = 0.f, s2 = 0.f;
        #pragma unroll 8
        for (int f = 0; f < 64; ++f) { float w = wr[f]; s1 += w * p1[f]; s2 += w * p2[f]; }
        B2s[i] = s1; B2d[i] = s2;
    } else if (b < SB_A + SB_I + SB_U + SB_G + SB_B + SB_O) {
        int i = (b - SB_A - SB_I - SB_U - SB_G - SB_B) * 256 + tid;
        if (i < NG) outp[i] = fcb3[0];
    } else if (b < SB_A + SB_I + SB_U + SB_G + SB_B + SB_O + SB_X) {
        // x -> fp16 (8 floats per thread)
        int i = (b - SB_A - SB_I - SB_U - SB_G - SB_B - SB_O) * 256 + tid;
        if (i < N_NODES * NF / 8) {
            const float4* src = (const float4*)x + (size_t)i * 2;
            float4 v0 = src[0], v1 = src[1];
            uint4 u;
            u.x = packh2(v0.x, v0.y); u.y = packh2(v0.z, v0.w);
            u.z = packh2(v1.x, v1.y); u.w = packh2(v1.z, v1.w);
            *(uint4*)(xh + (size_t)i * 8) = u;
        }
    } else if (b < SB_A + SB_I + SB_U + SB_G + SB_B + SB_O + SB_X + SB_F) {
        // fcW1/fcW2 -> fp16 (8 floats per thread); also pre-warms L3 for the MLP
        int i = (b - SB_A - SB_I - SB_U - SB_G - SB_B - SB_O - SB_X) * 256 + tid;
        const float* src = (i < 32768) ? fcW1 : fcW2;
        __half* dst = (i < 32768) ? fw1h : fw2h;
        int off = (i & 32767) * 8;
        const float4* s4 = (const float4*)(src + off);
        float4 v0 = s4[0], v1 = s4[1];
        uint4 u;
        u.x = packh2(v0.x, v0.y); u.y = packh2(v0.z, v0.w);
        u.z = packh2(v1.x, v1.y); u.w = packh2(v1.z, v1.w);
        *(uint4*)(dst + off) = u;
    } else {
        // edge histogram over dst (cnt pre-zeroed by memset; self-loop is +1 later)
        int e = (b - SB_A - SB_I - SB_U - SB_G - SB_B - SB_O - SB_X - SB_F) * 256 + tid;
        if (e < N_EDGES) atomicAdd(&cnt[ei[N_EDGES + e]], 1);
    }
}

// ---------------- CSR build ----------------

// off[i] = atomicAdd(total, cnt[i] + 1)  (+1 = self loop). Placement run-varying,
// per-node edge multiset identical -> output invariant.
__global__ void alloc_off_k(const int* __restrict__ cnt, int* __restrict__ off,
                            int* __restrict__ total) {
    int i = blockIdx.x * 256 + threadIdx.x;
    if (i < N_NODES) off[i] = atomicAdd(total, cnt[i] + 1);
}

__global__ void scatter_k(const int* __restrict__ ei, const int* __restrict__ off,
                          int* __restrict__ cur, int* __restrict__ ssrc) {
    int e = blockIdx.x * 256 + threadIdx.x;
    if (e < N_EDGES) {
        int s = ei[e];
        int d = ei[N_EDGES + e];
        int p = off[d] + atomicAdd(&cur[d], 1);
        ssrc[p] = s;
    } else if (e < N_EDGES + N_NODES) {
        int i = e - N_EDGES;                    // self loop
        int p = off[i] + atomicAdd(&cur[i], 1);
        ssrc[p] = i;
    }
}

// ---------------- layer-1 aggregation over fp16 x (wave per node, unroll 4) ----------------

__global__ __launch_bounds__(256) void agg1_k(
        const __half* __restrict__ xh, const float* __restrict__ as_,
        const float* __restrict__ ad_, const int* __restrict__ ssrc,
        const int* __restrict__ off, const int* __restrict__ cnt,
        __half* __restrict__ aggx1h) {
    int wv = __builtin_amdgcn_readfirstlane(blockIdx.x * 4 + (threadIdx.x >> 6));
    if (wv >= N_NODES) return;
    int lane = threadIdx.x & 63;
    int hd = lane >> 3, q = lane & 7;
    int beg = off[wv], end = beg + cnt[wv] + 1;   // +1 self loop
    float adv = ad_[wv * NH + hd];

    float4 acc = {0.f, 0.f, 0.f, 0.f};
    float wsum = 0.f;
    int j = beg;
    for (; j + 4 <= end; j += 4) {
        int s0 = ssrc[j], s1 = ssrc[j + 1], s2 = ssrc[j + 2], s3 = ssrc[j + 3];
        float e0 = as_[s0 * NH + hd], e1 = as_[s1 * NH + hd];
        float e2 = as_[s2 * NH + hd], e3 = as_[s3 * NH + hd];
        uint2 u0 = *(const uint2*)(xh + (size_t)s0 * NF + q * 4);
        uint2 u1 = *(const uint2*)(xh + (size_t)s1 * NF + q * 4);
        uint2 u2 = *(const uint2*)(xh + (size_t)s2 * NF + q * 4);
        uint2 u3 = *(const uint2*)(xh + (size_t)s3 * NF + q * 4);
        float w0 = edge_w(e0 + adv), w1 = edge_w(e1 + adv);
        float w2 = edge_w(e2 + adv), w3 = edge_w(e3 + adv);
        wsum += (w0 + w1) + (w2 + w3);
        float2 a01, a23;
        a01 = uph2(u0.x); a23 = uph2(u0.y);
        acc.x = fmaf(w0, a01.x, acc.x); acc.y = fmaf(w0, a01.y, acc.y);
        acc.z = fmaf(w0, a23.x, acc.z); acc.w = fmaf(w0, a23.y, acc.w);
        a01 = uph2(u1.x); a23 = uph2(u1.y);
        acc.x = fmaf(w1, a01.x, acc.x); acc.y = fmaf(w1, a01.y, acc.y);
        acc.z = fmaf(w1, a23.x, acc.z); acc.w = fmaf(w1, a23.y, acc.w);
        a01 = uph2(u2.x); a23 = uph2(u2.y);
        acc.x = fmaf(w2, a01.x, acc.x); acc.y = fmaf(w2, a01.y, acc.y);
        acc.z = fmaf(w2, a23.x, acc.z); acc.w = fmaf(w2, a23.y, acc.w);
        a01 = uph2(u3.x); a23 = uph2(u3.y);
        acc.x = fmaf(w3, a01.x, acc.x); acc.y = fmaf(w3, a01.y, acc.y);
        acc.z = fmaf(w3, a23.x, acc.z); acc.w = fmaf(w3, a23.y, acc.w);
    }
    for (; j < end; ++j) {
        int s0 = ssrc[j];
        float w0 = edge_w(as_[s0 * NH + hd] + adv);
        uint2 u0 = *(const uint2*)(xh + (size_t)s0 * NF + q * 4);
        wsum += w0;
        float2 a01 = uph2(u0.x), a23 = uph2(u0.y);
        acc.x = fmaf(w0, a01.x, acc.x); acc.y = fmaf(w0, a01.y, acc.y);
        acc.z = fmaf(w0, a23.x, acc.z); acc.w = fmaf(w0, a23.y, acc.w);
    }
    float inv = 1.f / wsum;
    uint2 st;
    st.x = packh2(acc.x * inv, acc.y * inv);
    st.y = packh2(acc.z * inv, acc.w * inv);
    *(uint2*)(aggx1h + (size_t)wv * 256 + lane * 4) = st;   // [hd*32 + q*4] == lane*4
}

// ---------------- proj1 + alpha2 fused: hxh = fp16(aggx1h @ U1 + b1); as_/ad_ from fp32 ----
// As padded [64][68]: float4 GEMM reads stay 16B-aligned (68k+r0 ≡ 0 mod 4),
// epilogue row-reads drop from 16-way to 8-way bank conflicts.

__global__ __launch_bounds__(256) void proj1a_k(
        const __half* __restrict__ Ah, const float* __restrict__ U1,
        const float* __restrict__ b1, const float* __restrict__ B2s,
        const float* __restrict__ B2d, __half* __restrict__ hxh,
        float* __restrict__ as_, float* __restrict__ ad_) {
    __shared__ float As[64][68];
    __shared__ float bs2[512], bd2[512];
    int t = threadIdx.x;
    int row0 = blockIdx.x * 64;
    for (int i = t; i < 512; i += 256) { bs2[i] = B2s[i]; bd2[i] = B2d[i]; }
    int rr = t & 63;
    int kb = (t >> 6) * 16;
    int r0 = (t >> 4) * 4;
    int c0 = (t & 15) * 4;
    float acc[4][4];
    #pragma unroll
    for (int i = 0; i < 4; ++i)
        #pragma unroll
        for (int j = 0; j < 4; ++j) acc[i][j] = 0.f;

    for (int kc = 0; kc < 256; kc += 64) {
        __syncthreads();
        {
            int grow = row0 + rr;
            const __half* ap = Ah + (size_t)grow * 256 + kc + kb;
            uint4 u0 = {0, 0, 0, 0}, u1 = {0, 0, 0, 0};
            if (grow < N_NODES) {
                u0 = *(const uint4*)(ap);
                u1 = *(const uint4*)(ap + 8);
            }
            float f[16];
            unpack8(u0, f);
            unpack8(u1, f + 8);
            #pragma unroll
            for (int i = 0; i < 16; ++i) As[kb + i][rr] = f[i];
        }
        __syncthreads();
        const float* wp = U1 + (size_t)kc * 64 + c0;
        #pragma unroll 4
        for (int k = 0; k < 64; ++k) {
            float4 a = *(const float4*)&As[k][r0];
            float4 w = *(const float4*)(wp + k * 64);
            acc[0][0] = fmaf(a.x, w.x, acc[0][0]); acc[0][1] = fmaf(a.x, w.y, acc[0][1]);
            acc[0][2] = fmaf(a.x, w.z, acc[0][2]); acc[0][3] = fmaf(a.x, w.w, acc[0][3]);
            acc[1][0] = fmaf(a.y, w.x, acc[1][0]); acc[1][1] = fmaf(a.y, w.y, acc[1][1]);
            acc[1][2] = fmaf(a.y, w.z, acc[1][2]); acc[1][3] = fmaf(a.y, w.w, acc[1][3]);
            acc[2][0] = fmaf(a.z, w.x, acc[2][0]); acc[2][1] = fmaf(a.z, w.y, acc[2][1]);
            acc[2][2] = fmaf(a.z, w.z, acc[2][2]); acc[2][3] = fmaf(a.z, w.w, acc[2][3]);
            acc[3][0] = fmaf(a.w, w.x, acc[3][0]); acc[3][1] = fmaf(a.w, w.y, acc[3][1]);
            acc[3][2] = fmaf(a.w, w.z, acc[3][2]); acc[3][3] = fmaf(a.w, w.w, acc[3][3]);
        }
    }
    __syncthreads();
    // write hx tile (with bias) into As as [row][col]
    float4 bv = *(const float4*)(b1 + c0);
    #pragma unroll
    for (int i = 0; i < 4; ++i) {
        As[r0 + i][c0 + 0] = acc[i][0] + bv.x;
        As[r0 + i][c0 + 1] = acc[i][1] + bv.y;
        As[r0 + i][c0 + 2] = acc[i][2] + bv.z;
        As[r0 + i][c0 + 3] = acc[i][3] + bv.w;
    }
    __syncthreads();
    // epilogue: thread t -> row = t>>2, col-slice sub = t&3 (cols sub*16..+16)
    int row = t >> 2, sub = t & 3;
    int grow = row0 + row;
    float ps[8], pd[8];
    #pragma unroll
    for (int hd = 0; hd < 8; ++hd) { ps[hd] = 0.f; pd[hd] = 0.f; }
    #pragma unroll 4
    for (int c2 = 0; c2 < 16; ++c2) {
        int c = sub * 16 + c2;
        float v = As[row][c];
        #pragma unroll
        for (int hd = 0; hd < 8; ++hd) {
            ps[hd] = fmaf(v, bs2[c * 8 + hd], ps[hd]);
            pd[hd] = fmaf(v, bd2[c * 8 + hd], pd[hd]);
        }
    }
    #pragma unroll
    for (int d = 1; d <= 2; d <<= 1) {
        #pragma unroll
        for (int hd = 0; hd < 8; ++hd) {
            ps[hd] += __shfl_xor(ps[hd], d, 64);
            pd[hd] += __shfl_xor(pd[hd], d, 64);
        }
    }
    if (grow < N_NODES) {
        int h0 = sub * 2;
        as_[grow * 8 + h0]     = ps[h0];
        as_[grow * 8 + h0 + 1] = ps[h0 + 1];
        ad_[grow * 8 + h0]     = pd[h0];
        ad_[grow * 8 + h0 + 1] = pd[h0 + 1];
        // fp16 store of cols sub*16..+16 (logits above were from fp32 - exact)
        const float* r = &As[row][sub * 16];
        uint4 u0, u1;
        u0.x = packh2(r[0],  r[1]);  u0.y = packh2(r[2],  r[3]);
        u0.z = packh2(r[4],  r[5]);  u0.w = packh2(r[6],  r[7]);
        u1.x = packh2(r[8],  r[9]);  u1.y = packh2(r[10], r[11]);
        u1.z = packh2(r[12], r[13]); u1.w = packh2(r[14], r[15]);
        *(uint4*)(hxh + (size_t)grow * 64 + sub * 16)     = u0;
        *(uint4*)(hxh + (size_t)grow * 64 + sub * 16 + 8) = u1;
    }
}

// ---------------- layer-2 agg (fp16 gather, packed fp16 accumulate) + pool + projection ----
// one block (4 waves) per graph; lane owns channels lane*8..+8 (head = lane>>3).
// fp16 accumulation is overflow-safe here: layer-2 logits sigma ~0.2 -> w in ~[0.5,2].

__device__ inline void acc8pk(float w, uint4 u, __half2& a0, __half2& a1,
                              __half2& a2, __half2& a3) {
    __half2 wh = __float2half2_rn(w);
    union { uint4 u4; __half2 h[4]; } c;
    c.u4 = u;
    a0 = __hfma2(wh, c.h[0], a0);
    a1 = __hfma2(wh, c.h[1], a1);
    a2 = __hfma2(wh, c.h[2], a2);
    a3 = __hfma2(wh, c.h[3], a3);
}

__global__ __launch_bounds__(256) void agg2gp_k(
        const __half* __restrict__ hxh, const float* __restrict__ as_,
        const float* __restrict__ ad_, const int* __restrict__ ssrc,
        const int* __restrict__ off, const int* __restrict__ cnt,
        const int* __restrict__ goff, const float* __restrict__ W2,
        const float* __restrict__ b2, float* __restrict__ g0) {
    int g = blockIdx.x;
    int w = threadIdx.x >> 6;
    int lane = threadIdx.x & 63;
    int hd = lane >> 3, q = lane & 7;
    int nbeg = goff[g], nend = goff[g + 1];

    __shared__ float sp[4][512];

    float4 p0 = {0.f, 0.f, 0.f, 0.f}, p1 = {0.f, 0.f, 0.f, 0.f};

    for (int nd0 = nbeg + w; nd0 < nend; nd0 += 4) {
        int nd = __builtin_amdgcn_readfirstlane(nd0);
        int beg = off[nd], end = beg + cnt[nd] + 1;   // +1 self loop
        float adv = ad_[nd * NH + hd];

        __half2 z = __float2half2_rn(0.f);
        __half2 ah0 = z, ah1 = z, ah2 = z, ah3 = z;
        float wsum = 0.f;
        int j = beg;
        for (; j + 4 <= end; j += 4) {
            int s0 = ssrc[j], s1 = ssrc[j + 1], s2 = ssrc[j + 2], s3 = ssrc[j + 3];
            float e0 = as_[s0 * NH + hd], e1 = as_[s1 * NH + hd];
            float e2 = as_[s2 * NH + hd], e3 = as_[s3 * NH + hd];
            uint4 u0 = *(const uint4*)(hxh + (size_t)s0 * DE + q * 8);
            uint4 u1 = *(const uint4*)(hxh + (size_t)s1 * DE + q * 8);
            uint4 u2 = *(const uint4*)(hxh + (size_t)s2 * DE + q * 8);
            uint4 u3 = *(const uint4*)(hxh + (size_t)s3 * DE + q * 8);
            float w0 = edge_w(e0 + adv), w1 = edge_w(e1 + adv);
            float w2 = edge_w(e2 + adv), w3 = edge_w(e3 + adv);
            wsum += (w0 + w1) + (w2 + w3);
            acc8pk(w0, u0, ah0, ah1, ah2, ah3);
            acc8pk(w1, u1, ah0, ah1, ah2, ah3);
            acc8pk(w2, u2, ah0, ah1, ah2, ah3);
            acc8pk(w3, u3, ah0, ah1, ah2, ah3);
        }
        for (; j < end; ++j) {
            int s0 = ssrc[j];
            float w0 = edge_w(as_[s0 * NH + hd] + adv);
            uint4 u0 = *(const uint4*)(hxh + (size_t)s0 * DE + q * 8);
            wsum += w0;
            acc8pk(w0, u0, ah0, ah1, ah2, ah3);
        }
        float inv = 1.f / wsum;
        float2 f0 = __half22float2(ah0), f1 = __half22float2(ah1);
        float2 f2 = __half22float2(ah2), f3 = __half22float2(ah3);
        p0.x = fmaf(inv, f0.x, p0.x); p0.y = fmaf(inv, f0.y, p0.y);
        p0.z = fmaf(inv, f1.x, p0.z); p0.w = fmaf(inv, f1.y, p0.w);
        p1.x = fmaf(inv, f2.x, p1.x); p1.y = fmaf(inv, f2.y, p1.y);
        p1.z = fmaf(inv, f3.x, p1.z); p1.w = fmaf(inv, f3.y, p1.w);
    }

    *(float4*)&sp[w][lane * 8]     = p0;
    *(float4*)&sp[w][lane * 8 + 4] = p1;
    __syncthreads();
    int t = threadIdx.x;
    {
        float s0 = sp[0][t] + sp[1][t] + sp[2][t] + sp[3][t];
        float s1 = sp[0][t + 256] + sp[1][t + 256] + sp[2][t + 256] + sp[3][t + 256];
        sp[0][t] = s0;
        sp[0][t + 256] = s1;
    }
    __syncthreads();
    int cn = nend - nbeg;
    #pragma unroll
    for (int half = 0; half < 2; ++half) {
        int ch = t + half * 256;
        int hd2 = ch >> 6;
        float acc = (float)cn * b2[ch];
        const float* pp = &sp[0][hd2 * 64];
        #pragma unroll 8
        for (int c = 0; c < 64; ++c)
            acc = fmaf(pp[c], W2[(size_t)c * 512 + ch], acc);   // coalesced: ch contiguous across threads
        g0[(size_t)g * CT + ch] = acc;
    }
}

// ---------------- MLP GEMM: fp16 W, 16x64 tiles, 128 threads, 1000 blocks ----------------
// thread = 1 row x 8 cols (one uint4 of W per k). grid (125, 8).
// FINAL fuses @fcW3 via 8-lane shfl reduce + atomicAdd.

template<bool FINAL>
__global__ __launch_bounds__(128) void tgemm_k(
        const float* __restrict__ A, const __half* __restrict__ Wh,
        const float* __restrict__ bias, float* __restrict__ Y,
        const float* __restrict__ W3, float* __restrict__ outp) {
    constexpr int K = 512, N = 512;
    __shared__ float As[64][17];
    int t = threadIdx.x;          // 0..127
    int row0 = blockIdx.x * 16;
    int col0 = blockIdx.y * 64;
    int r = t >> 3;               // 0..15
    int cg = t & 7;
    int c0 = cg * 8;
    float acc[8] = {0.f, 0.f, 0.f, 0.f, 0.f, 0.f, 0.f, 0.f};

    for (int kc = 0; kc < K; kc += 64) {
        if (kc) __syncthreads();
        {   // stage A tile [16 rows][64 k]: thread loads 8 floats of row r
            const float* ap = A + (size_t)(row0 + r) * K + kc + cg * 8;
            float4 v0 = *(const float4*)(ap);
            float4 v1 = *(const float4*)(ap + 4);
            As[cg * 8 + 0][r] = v0.x; As[cg * 8 + 1][r] = v0.y;
            As[cg * 8 + 2][r] = v0.z; As[cg * 8 + 3][r] = v0.w;
            As[cg * 8 + 4][r] = v1.x; As[cg * 8 + 5][r] = v1.y;
            As[cg * 8 + 6][r] = v1.z; As[cg * 8 + 7][r] = v1.w;
        }
        __syncthreads();
        const __half* wp = Wh + (size_t)kc * N + col0 + c0;
        #pragma unroll 8
        for (int k = 0; k < 64; ++k) {
            float a = As[k][r];
            uint4 u = *(const uint4*)(wp + (size_t)k * N);
            float f[8];
            unpack8(u, f);
            acc[0] = fmaf(a, f[0], acc[0]); acc[1] = fmaf(a, f[1], acc[1]);
            acc[2] = fmaf(a, f[2], acc[2]); acc[3] = fmaf(a, f[3], acc[3]);
            acc[4] = fmaf(a, f[4], acc[4]); acc[5] = fmaf(a, f[5], acc[5]);
            acc[6] = fmaf(a, f[6], acc[6]); acc[7] = fmaf(a, f[7], acc[7]);
        }
    }
    float4 bv0 = *(const float4*)(bias + col0 + c0);
    float4 bv1 = *(const float4*)(bias + col0 + c0 + 4);
    float o[8];
    o[0] = fmaxf(acc[0] + bv0.x, 0.f); o[1] = fmaxf(acc[1] + bv0.y, 0.f);
    o[2] = fmaxf(acc[2] + bv0.z, 0.f); o[3] = fmaxf(acc[3] + bv0.w, 0.f);
    o[4] = fmaxf(acc[4] + bv1.x, 0.f); o[5] = fmaxf(acc[5] + bv1.y, 0.f);
    o[6] = fmaxf(acc[6] + bv1.z, 0.f); o[7] = fmaxf(acc[7] + bv1.w, 0.f);
    if constexpr (!FINAL) {
        float* yp = Y + (size_t)(row0 + r) * N + col0 + c0;
        float4 s0 = {o[0], o[1], o[2], o[3]};
        float4 s1 = {o[4], o[5], o[6], o[7]};
        *(float4*)(yp)     = s0;
        *(float4*)(yp + 4) = s1;
    } else {
        float4 w30 = *(const float4*)(W3 + col0 + c0);
        float4 w31 = *(const float4*)(W3 + col0 + c0 + 4);
        float s = o[0] * w30.x + o[1] * w30.y + o[2] * w30.z + o[3] * w30.w
                + o[4] * w31.x + o[5] * w31.y + o[6] * w31.z + o[7] * w31.w;
        s += __shfl_xor(s, 1, 64);
        s += __shfl_xor(s, 2, 64);
        s += __shfl_xor(s, 4, 64);
        if (cg == 0) atomicAdd(&outp[row0 + r], s);
    }
}

// ---------------- launch ----------------

extern "C" void kernel_launch(void* const* d_in, const int* in_sizes, int n_in,
                              void* d_out, int out_size, void* d_ws, size_t ws_size,
                              hipStream_t stream) {
    const float* x     = (const float*)d_in[0];
    const int*   ei    = (const int*)d_in[1];
    const int*   batch = (const int*)d_in[2];
    const float* W1    = (const float*)d_in[3];
    const float* asrc1 = (const float*)d_in[4];
    const float* adst1 = (const float*)d_in[5];
    const float* b1    = (const float*)d_in[6];
    const float* W2    = (const float*)d_in[7];
    const float* asrc2 = (const float*)d_in[8];
    const float* adst2 = (const float*)d_in[9];
    const float* b2    = (const float*)d_in[10];
    const float* fcW1  = (const float*)d_in[11];
    const float* fcb1  = (const float*)d_in[12];
    const float* fcW2  = (const float*)d_in[13];
    const float* fcb2  = (const float*)d_in[14];
    const float* fcW3  = (const float*)d_in[15];
    const float* fcb3  = (const float*)d_in[16];
    float* outp = (float*)d_out;

    char* p = (char*)d_ws;
    auto take = [&](size_t bytes) {
        char* r = p;
        p += (bytes + 255) & ~(size_t)255;
        return r;
    };
    __half* aggx1h = (__half*)take((size_t)N_NODES * 256 * 2); // 25.6 MB fp16
    __half* hxh    = (__half*)take((size_t)N_NODES * DE * 2);  // 6.4 MB fp16
    __half* xh     = (__half*)take((size_t)N_NODES * NF * 2);  // 3.2 MB fp16
    float*  as_    = (float*)take((size_t)N_NODES * NH * 4);
    float*  ad_    = (float*)take((size_t)N_NODES * NH * 4);
    int*    ssrc   = (int*)take((size_t)(N_EDGES + N_NODES) * 4);
    int*    offv   = (int*)take((size_t)N_NODES * 4);
    int*    cntv   = (int*)take((size_t)N_NODES * 4);
    int*    cur    = (int*)take((size_t)N_NODES * 4);
    int*    total  = (int*)take(256);
    int*    goff   = (int*)take((size_t)(NG + 1) * 4);
    float*  B2s    = (float*)take(512 * 4);
    float*  B2d    = (float*)take(512 * 4);
    float*  U1     = (float*)take(256 * 64 * 4);
    __half* fw1h   = (__half*)take((size_t)DMLP * DMLP * 2);   // 512 KB fp16
    __half* fw2h   = (__half*)take((size_t)DMLP * DMLP * 2);   // 512 KB fp16
    float*  g0     = (float*)take((size_t)NG * DMLP * 4);
    float*  g1     = (float*)take((size_t)NG * DMLP * 4);

    // 0. zero the edge histogram (hist is folded into setup_k)
    hipMemsetAsync(cntv, 0, (size_t)N_NODES * 4, stream);

    // 1. all dependency-free prep + edge histogram (overlapped)
    setup_k<<<SB_A + SB_I + SB_U + SB_G + SB_B + SB_O + SB_X + SB_F + SB_H, 256, 0, stream>>>(
        x, W1, asrc1, adst1, W2, asrc2, adst2, batch, fcb3, fcW1, fcW2, ei,
        cntv, cur, total, U1, goff, B2s, B2d, as_, ad_, outp, xh, fw1h, fw2h);

    // 2-3. CSR build (offsets include +1 slot per node for the self loop)
    alloc_off_k<<<(N_NODES + 255) / 256, 256, 0, stream>>>(cntv, offv, total);
    scatter_k<<<(N_EDGES + N_NODES + 255) / 256, 256, 0, stream>>>(ei, offv, cur, ssrc);

    // 4-5. layer 1: aggregate fp16 x per head (fp16 out); fused projection + alpha2
    agg1_k<<<(N_NODES + 3) / 4, 256, 0, stream>>>(xh, as_, ad_, ssrc, offv, cntv, aggx1h);
    proj1a_k<<<(N_NODES + 63) / 64, 256, 0, stream>>>(aggx1h, U1, b1, B2s, B2d, hxh, as_, ad_);

    // 6. layer 2: fused agg (fp16 gather, pk-fp16 accumulate) + pool + projection
    agg2gp_k<<<NG, 256, 0, stream>>>(hxh, as_, ad_, ssrc, offv, cntv, goff, W2, b2, g0);

    // 7-8. MLP head: fp16 W, 16x64 tiles, 1000 blocks (final projection fused into fc2)
    {
        dim3 grid(NG / 16, DMLP / 64);   // 125 x 8
        tgemm_k<false><<<grid, 128, 0, stream>>>(g0, fw1h, fcb1, g1, nullptr, nullptr);
        tgemm_k<true><<<grid, 128, 0, stream>>>(g1, fw2h, fcb2, nullptr, fcW3, outp);
    }
}